// Round 17
// baseline (5440.471 us; speedup 1.0000x reference)
//
#include <hip/hip_runtime.h>
#include <cstdint>
#include <cstddef>

#define DEVINL __device__ __forceinline__

typedef float f32x4 __attribute__((ext_vector_type(4)));

DEVINL float ntload1(const float* p) {
    return __builtin_nontemporal_load(p);
}
DEVINL f32x4 ld4(const float* p) {
    return *reinterpret_cast<const f32x4*>(p);
}

// ---------- math helpers ----------
DEVINL float frcp(float x) { return __builtin_amdgcn_rcpf(x); }
DEVINL float ftanh_fast(float x) {
    float e = __expf(2.0f * x);
    return 1.0f - 2.0f * frcp(e + 1.0f);
}
DEVINL float sig_precise(float x) { return 1.0f / (1.0f + expf(-x)); }
DEVINL float tanh_precise(float x) { return tanhf(x); }

// ---------- sizes ----------
#define BB 128
#define SS 128
#define IND 16
#define DD 256
#define HH 256
#define H4 1024
#define H2 512

// =====================================================================
// K1: emb = LayerNorm(tanh(x @ proj_W.T + proj_b))   (one block per row)
// =====================================================================
__global__ __launch_bounds__(256) void k_proj_ln(
    const float* __restrict__ x, const float* __restrict__ projW,
    const float* __restrict__ projB, const float* __restrict__ ln_g,
    const float* __restrict__ ln_b, float* __restrict__ emb)
{
    __shared__ float Wl[256 * 17];
    __shared__ float xl[16];
    __shared__ float red[256];
    const int row = blockIdx.x;
    const int tid = threadIdx.x;
    for (int idx = tid; idx < 256 * 16; idx += 256) {
        int d = idx >> 4, i = idx & 15;
        Wl[d * 17 + i] = projW[idx];
    }
    if (tid < 16) xl[tid] = x[row * 16 + tid];
    __syncthreads();
    float acc = projB[tid];
#pragma unroll
    for (int i = 0; i < 16; ++i) acc = fmaf(Wl[tid * 17 + i], xl[i], acc);
    float v = tanh_precise(acc);
    red[tid] = v;
    __syncthreads();
    for (int s2 = 128; s2 > 0; s2 >>= 1) { if (tid < s2) red[tid] += red[tid + s2]; __syncthreads(); }
    float mean = red[0] * (1.0f / 256.0f);
    __syncthreads();
    float dlt = v - mean;
    red[tid] = dlt * dlt;
    __syncthreads();
    for (int s2 = 128; s2 > 0; s2 >>= 1) { if (tid < s2) red[tid] += red[tid + s2]; __syncthreads(); }
    float var = red[0] * (1.0f / 256.0f);
    float rs = 1.0f / sqrtf(var + 1e-5f);
    emb[(size_t)row * 256 + tid] = dlt * rs * ln_g[tid] + ln_b[tid];
}

// =====================================================================
// K2: fp32 GEMM-NT, double-buffered LDS (1 barrier/K-step, loads of
// tile k+1 overlap compute of tile k). tile 128x128, 256 thr, Kstep 16.
// flags: 1=tanh
// =====================================================================
__global__ __launch_bounds__(256) void k_gemm_nt(
    const float* __restrict__ A, int lda,
    const float* __restrict__ Bm,
    float* __restrict__ C,
    int M, int N, int K,
    const float* __restrict__ bias1, const float* __restrict__ bias2,
    int flags)
{
    __shared__ __align__(16) float As[2][16][132];
    __shared__ __align__(16) float Bs[2][16][132];
    const int tid = threadIdx.x;
    const int m0 = blockIdx.x * 128;
    const int n0 = blockIdx.y * 128;
    const int r = tid >> 1, half = tid & 1;
    const int tm = tid & 15, tn = tid >> 4;
    float acc[8][8];
#pragma unroll
    for (int i = 0; i < 8; ++i)
#pragma unroll
        for (int j = 0; j < 8; ++j) acc[i][j] = 0.0f;

    const int nsteps = K >> 4;
    // prologue: load tile 0 and stage into buffer 0
    {
        const float4* pa = reinterpret_cast<const float4*>(&A[(size_t)(m0 + r) * lda + half * 8]);
        float4 a0 = pa[0], a1 = pa[1];
        const float4* pb = reinterpret_cast<const float4*>(&Bm[(size_t)(n0 + r) * K + half * 8]);
        float4 b0 = pb[0], b1 = pb[1];
        const int kb = half * 8;
        As[0][kb + 0][r] = a0.x; As[0][kb + 1][r] = a0.y; As[0][kb + 2][r] = a0.z; As[0][kb + 3][r] = a0.w;
        As[0][kb + 4][r] = a1.x; As[0][kb + 5][r] = a1.y; As[0][kb + 6][r] = a1.z; As[0][kb + 7][r] = a1.w;
        Bs[0][kb + 0][r] = b0.x; Bs[0][kb + 1][r] = b0.y; Bs[0][kb + 2][r] = b0.z; Bs[0][kb + 3][r] = b0.w;
        Bs[0][kb + 4][r] = b1.x; Bs[0][kb + 5][r] = b1.y; Bs[0][kb + 6][r] = b1.z; Bs[0][kb + 7][r] = b1.w;
    }
    __syncthreads();

    for (int s = 0; s < nsteps; ++s) {
        const int cur = s & 1;
        float4 na0, na1, nb0, nb1;
        const bool hasNext = (s + 1 < nsteps);
        if (hasNext) {
            const int k0 = (s + 1) << 4;
            const float4* pa = reinterpret_cast<const float4*>(&A[(size_t)(m0 + r) * lda + k0 + half * 8]);
            na0 = pa[0]; na1 = pa[1];
            const float4* pb = reinterpret_cast<const float4*>(&Bm[(size_t)(n0 + r) * K + k0 + half * 8]);
            nb0 = pb[0]; nb1 = pb[1];
        }
#pragma unroll
        for (int kk = 0; kk < 16; ++kk) {
            const float4 xa0 = *reinterpret_cast<const float4*>(&As[cur][kk][tm * 8]);
            const float4 xa1 = *reinterpret_cast<const float4*>(&As[cur][kk][tm * 8 + 4]);
            const float4 xb0 = *reinterpret_cast<const float4*>(&Bs[cur][kk][tn * 8]);
            const float4 xb1 = *reinterpret_cast<const float4*>(&Bs[cur][kk][tn * 8 + 4]);
            const float av[8] = {xa0.x, xa0.y, xa0.z, xa0.w, xa1.x, xa1.y, xa1.z, xa1.w};
            const float bv[8] = {xb0.x, xb0.y, xb0.z, xb0.w, xb1.x, xb1.y, xb1.z, xb1.w};
#pragma unroll
            for (int i = 0; i < 8; ++i)
#pragma unroll
                for (int j = 0; j < 8; ++j) acc[i][j] = fmaf(av[i], bv[j], acc[i][j]);
        }
        if (hasNext) {
            const int nb2 = cur ^ 1;
            const int kb = half * 8;
            As[nb2][kb + 0][r] = na0.x; As[nb2][kb + 1][r] = na0.y; As[nb2][kb + 2][r] = na0.z; As[nb2][kb + 3][r] = na0.w;
            As[nb2][kb + 4][r] = na1.x; As[nb2][kb + 5][r] = na1.y; As[nb2][kb + 6][r] = na1.z; As[nb2][kb + 7][r] = na1.w;
            Bs[nb2][kb + 0][r] = nb0.x; Bs[nb2][kb + 1][r] = nb0.y; Bs[nb2][kb + 2][r] = nb0.z; Bs[nb2][kb + 3][r] = nb0.w;
            Bs[nb2][kb + 4][r] = nb1.x; Bs[nb2][kb + 5][r] = nb1.y; Bs[nb2][kb + 6][r] = nb1.z; Bs[nb2][kb + 7][r] = nb1.w;
        }
        __syncthreads();
    }
    const int nb = n0 + tn * 8;
    float bias[8];
#pragma unroll
    for (int j = 0; j < 8; ++j) {
        float bbv = 0.0f;
        if (bias1) bbv += bias1[nb + j];
        if (bias2) bbv += bias2[nb + j];
        bias[j] = bbv;
    }
#pragma unroll
    for (int i = 0; i < 8; ++i) {
        const size_t m = (size_t)(m0 + tm * 8 + i);
        float o[8];
#pragma unroll
        for (int j = 0; j < 8; ++j) {
            float vv = acc[i][j] + bias[j];
            if (flags & 1) vv = tanh_precise(vv);
            o[j] = vv;
        }
        float4* pc = reinterpret_cast<float4*>(&C[m * N + nb]);
        pc[0] = make_float4(o[0], o[1], o[2], o[3]);
        pc[1] = make_float4(o[4], o[5], o[6], o[7]);
    }
}

// =====================================================================
// K3: bidirectional LSTM (R12 proven): 256 WGs x 512 threads, ONE chain
// per WG. Compact dbuf W-pass (16 rounds of 64 rows).
// =====================================================================
__global__ __launch_bounds__(512, 2) void k_lstm(
    const float* __restrict__ Whh_f, const float* __restrict__ Whh_b,
    const float* __restrict__ xf, const float* __restrict__ xb,
    float* __restrict__ enc, float* __restrict__ hT, float* __restrict__ cT)
{
    const int wg = blockIdx.x;       // 0..255
    const int dir = wg >> 7;
    const int bat = wg & 127;
    const float* W = dir ? Whh_b : Whh_f;
    const float* xin = dir ? xb : xf;
    const int tid = threadIdx.x;
    const int oct = tid & 7, jg = tid >> 3;   // jg 0..63

    __shared__ __align__(16) float h_lds[256];
    __shared__ float pre_lds[1024];

    if (tid < 256) h_lds[tid] = 0.0f;
    float c_reg = 0.0f;
    __syncthreads();

    for (int t = 0; t < SS; ++t) {
        const int st = dir ? (SS - 1 - t) : t;
        float hreg[32];
#pragma unroll
        for (int i = 0; i < 8; ++i) {
            f32x4 v = ld4(&h_lds[i * 32 + oct * 4]);
            hreg[i * 4 + 0] = v.x; hreg[i * 4 + 1] = v.y;
            hreg[i * 4 + 2] = v.z; hreg[i * 4 + 3] = v.w;
        }
        {
            f32x4 wA[8], wB[8];
            {
                const float* bp = &W[(size_t)jg * 256 + oct * 4];
#pragma unroll
                for (int i = 0; i < 8; ++i) wA[i] = ld4(bp + i * 32);
            }
            auto wstep = [&](f32x4 (&cur)[8], f32x4 (&nxt)[8], int q) {
                if (q < 15) {
                    const float* bp = &W[(size_t)((q + 1) * 64 + jg) * 256 + oct * 4];
#pragma unroll
                    for (int i = 0; i < 8; ++i) nxt[i] = ld4(bp + i * 32);
                }
                float a0 = 0.0f;
#pragma unroll
                for (int i = 0; i < 8; ++i) {
                    a0 = fmaf(cur[i].x, hreg[i * 4 + 0], a0);
                    a0 = fmaf(cur[i].y, hreg[i * 4 + 1], a0);
                    a0 = fmaf(cur[i].z, hreg[i * 4 + 2], a0);
                    a0 = fmaf(cur[i].w, hreg[i * 4 + 3], a0);
                }
                a0 += __shfl_xor(a0, 1); a0 += __shfl_xor(a0, 2); a0 += __shfl_xor(a0, 4);
                if (oct == 0) pre_lds[q * 64 + jg] = a0;
            };
#pragma unroll 1
            for (int q = 0; q < 16; q += 2) { wstep(wA, wB, q); wstep(wB, wA, q + 1); }
        }
        __syncthreads();
        if (tid < 256) {
            const int gc = tid;
            const float* xrow = &xin[((size_t)bat * SS + st) * 1024];
            float pi = pre_lds[gc]       + ntload1(&xrow[gc]);
            float pf = pre_lds[256 + gc] + ntload1(&xrow[256 + gc]);
            float pg = pre_lds[512 + gc] + ntload1(&xrow[512 + gc]);
            float po = pre_lds[768 + gc] + ntload1(&xrow[768 + gc]);
            float ig = sig_precise(pi), fg = sig_precise(pf);
            float gg = tanh_precise(pg), og = sig_precise(po);
            float cn = fmaf(fg, c_reg, ig * gg);
            float hn = og * tanh_precise(cn);
            c_reg = cn;
            h_lds[gc] = hn;
            enc[((size_t)bat * SS + st) * 512 + dir * 256 + gc] = hn;
            if (t == SS - 1) {
                hT[(size_t)bat * 512 + dir * 256 + gc] = hn;
                cT[(size_t)bat * 512 + dir * 256 + gc] = cn;
            }
        }
        __syncthreads();
    }
}

// =====================================================================
// K5: pre0[b][j] = mean_s encW[b][s][j]
// =====================================================================
__global__ __launch_bounds__(256) void k_meanw(const float* __restrict__ encW, float* __restrict__ pre0)
{
    const int b = blockIdx.x;
    const int tid = threadIdx.x;
    const float4* base = reinterpret_cast<const float4*>(&encW[(size_t)b * SS * 1024]);
    float sx = 0.0f, sy = 0.0f, sz = 0.0f, sw = 0.0f;
    for (int s = 0; s < SS; ++s) {
        float4 v = base[s * 256 + tid];
        sx += v.x; sy += v.y; sz += v.z; sw += v.w;
    }
    float4* out = reinterpret_cast<float4*>(&pre0[(size_t)b * 1024]);
    out[tid] = make_float4(sx * (1.0f / 128.0f), sy * (1.0f / 128.0f), sz * (1.0f / 128.0f), sw * (1.0f / 128.0f));
}

// =====================================================================
// K6: pointer decoder (R16 verbatim): 128 WGs x 1024 threads,
// wave-specialized, 7 barriers/step.
// =====================================================================
__global__ __launch_bounds__(1024) void k_decoder(
    const float* __restrict__ Whh_d,
    const float* __restrict__ gW2, const float* __restrict__ pW2,
    const float* __restrict__ gv, const float* __restrict__ pv,
    const float* __restrict__ g_ref, const float* __restrict__ p_ref,
    const float* __restrict__ encP, const float* __restrict__ encW,
    const float* __restrict__ pre0, const float* __restrict__ h0,
    const float* __restrict__ c0,
    float* __restrict__ out_logits, float* __restrict__ out_ptrs)
{
    const int b = blockIdx.x;             // batch
    const int tid = threadIdx.x;
    const int oct = tid & 7;
    const int jg128 = tid >> 3;           // 0..127 (prologue)
    const int wid = tid >> 6, lane = tid & 63;
    const int ajg = (tid & 511) >> 3;     // 0..63 (both sides)

    __shared__ __align__(16) float h_lds[256];
    __shared__ float c_lds[256];
    __shared__ float wacc_lds[1024];
    __shared__ __align__(16) float hgp[512];   // [0..255]=hg, [256..511]=hp1
    __shared__ __align__(16) float hp_lds[256];
    __shared__ __align__(16) float gv_lds[256];
    __shared__ __align__(16) float pv_lds[256];
    __shared__ float sc_arr[128];
    __shared__ __align__(16) float hp_half[8][256];
    __shared__ int mask_lds[128];
    __shared__ int ulist[128];
    __shared__ int ucount_s;
    __shared__ float Z_s;
    __shared__ int sel_s;

    if (tid < 256) {
        gv_lds[tid] = gv[tid];
        pv_lds[tid] = pv[tid];
        h_lds[tid] = h0[(size_t)b * 256 + tid];
        c_lds[tid] = c0[(size_t)b * 256 + tid];
    }
    if (tid < 128) mask_lds[tid] = 0;
    if (tid == 0) sel_s = -1;
    const float* grefb = g_ref + (size_t)b * SS * 256;
    const float* prefb = p_ref + (size_t)b * SS * 256;
    const float* encPb = encP + (size_t)b * SS * 256;
    const float* pre0b = pre0 + (size_t)b * 1024;
    const float* encWb = encW + (size_t)b * SS * 1024;
    __syncthreads();

    // ---- prologue: wacc = Whh_d @ h0 (all waves; 8 rounds of 128 rows) ----
    {
        float hreg0[32];
#pragma unroll
        for (int i = 0; i < 8; ++i) {
            f32x4 v = ld4(&h_lds[i * 32 + oct * 4]);
            hreg0[i * 4 + 0] = v.x; hreg0[i * 4 + 1] = v.y;
            hreg0[i * 4 + 2] = v.z; hreg0[i * 4 + 3] = v.w;
        }
        f32x4 wA[8], wB[8];
        {
            const float* bp = &Whh_d[(size_t)jg128 * 256 + oct * 4];
#pragma unroll
            for (int i = 0; i < 8; ++i) wA[i] = ld4(bp + i * 32);
        }
        auto pw = [&](f32x4 (&cur)[8], f32x4 (&nxt)[8], int q) {
            if (q < 7) {
                const float* bp = &Whh_d[(size_t)((q + 1) * 128 + jg128) * 256 + oct * 4];
#pragma unroll
                for (int i = 0; i < 8; ++i) nxt[i] = ld4(bp + i * 32);
            }
            float a0 = 0.0f;
#pragma unroll
            for (int i = 0; i < 8; ++i) {
                a0 = fmaf(cur[i].x, hreg0[i * 4 + 0], a0);
                a0 = fmaf(cur[i].y, hreg0[i * 4 + 1], a0);
                a0 = fmaf(cur[i].z, hreg0[i * 4 + 2], a0);
                a0 = fmaf(cur[i].w, hreg0[i * 4 + 3], a0);
            }
            a0 += __shfl_xor(a0, 1); a0 += __shfl_xor(a0, 2); a0 += __shfl_xor(a0, 4);
            if (oct == 0) wacc_lds[q * 128 + jg128] = a0;
        };
#pragma unroll 1
        for (int q = 0; q < 8; q += 2) { pw(wA, wB, q); pw(wB, wA, q + 1); }
    }
    __syncthreads();

    for (int t = 0; t < SS; ++t) {
        // ---- segG: gates (direct row loads) | ulist (wave 8) | sc init ----
        if (tid < 256) {
            const int ch = tid;
            const int sel = sel_s;
            const float* src = (sel < 0) ? pre0b : &encWb[(size_t)sel * 1024];
            float r0 = src[ch], r1 = src[256 + ch], r2 = src[512 + ch], r3 = src[768 + ch];
            float pi = wacc_lds[ch]       + r0;
            float pf = wacc_lds[256 + ch] + r1;
            float pg = wacc_lds[512 + ch] + r2;
            float po = wacc_lds[768 + ch] + r3;
            float ig = sig_precise(pi), fg = sig_precise(pf);
            float gg = tanh_precise(pg), og = sig_precise(po);
            float cn = fmaf(fg, c_lds[ch], ig * gg);
            float hn = og * tanh_precise(cn);
            c_lds[ch] = cn;
            h_lds[ch] = hn;
        } else if (tid < 384) {
            sc_arr[tid - 256] = -1e9f;
        } else if (tid >= 512 && tid < 576) {
            const unsigned long long lowmask = (1ull << lane) - 1ull;
            const bool u0 = (mask_lds[lane] == 0);
            const unsigned long long b0m = __ballot(u0);
            if (u0) ulist[__popcll(b0m & lowmask)] = lane;
            const bool u1 = (mask_lds[lane + 64] == 0);
            const unsigned long long b1m = __ballot(u1);
            const int c0 = __popcll(b0m);
            if (u1) ulist[c0 + __popcll(b1m & lowmask)] = lane + 64;
            if (lane == 0) ucount_s = c0 + __popcll(b1m);
        }
        __syncthreads();
        // h_t -> regs (both sides)
        float hreg[32];
#pragma unroll
        for (int i = 0; i < 8; ++i) {
            f32x4 v = ld4(&h_lds[i * 32 + oct * 4]);
            hreg[i * 4 + 0] = v.x; hreg[i * 4 + 1] = v.y;
            hreg[i * 4 + 2] = v.z; hreg[i * 4 + 3] = v.w;
        }
        // weight-side round: wacc(t+1)[q*64+ajg] = Whh_d row @ h_t
        auto wround = [&](int q) {
            const float* bp = &Whh_d[(size_t)(q * 64 + ajg) * 256 + oct * 4];
            f32x4 w[8];
#pragma unroll
            for (int i = 0; i < 8; ++i) w[i] = ld4(bp + i * 32);
            float a0 = 0.0f;
#pragma unroll
            for (int i = 0; i < 8; ++i) {
                a0 = fmaf(w[i].x, hreg[i * 4 + 0], a0);
                a0 = fmaf(w[i].y, hreg[i * 4 + 1], a0);
                a0 = fmaf(w[i].z, hreg[i * 4 + 2], a0);
                a0 = fmaf(w[i].w, hreg[i * 4 + 3], a0);
            }
            a0 += __shfl_xor(a0, 1); a0 += __shfl_xor(a0, 2); a0 += __shfl_xor(a0, 4);
            if (oct == 0) wacc_lds[q * 64 + ajg] = a0;
        };
        // ---- seg0: attn hgp (8 dbuf rounds); weight rounds 0-3 ----
        if (tid < 512) {
            f32x4 wA[8], wB[8];
            {
                const float* src0 = (ajg < 256) ? &gW2[(size_t)ajg * 256] : &pW2[(size_t)(ajg - 256) * 256];
#pragma unroll
                for (int i = 0; i < 8; ++i) wA[i] = ld4(src0 + oct * 4 + i * 32);
            }
            auto p3 = [&](f32x4 (&cur)[8], f32x4 (&nxt)[8], int q) {
                if (q < 7) {
                    const int r2 = (q + 1) * 64 + ajg;
                    const float* src = (r2 < 256) ? &gW2[(size_t)r2 * 256] : &pW2[(size_t)(r2 - 256) * 256];
#pragma unroll
                    for (int i = 0; i < 8; ++i) nxt[i] = ld4(src + oct * 4 + i * 32);
                }
                float a0 = 0.0f;
#pragma unroll
                for (int i = 0; i < 8; ++i) {
                    a0 = fmaf(cur[i].x, hreg[i * 4 + 0], a0);
                    a0 = fmaf(cur[i].y, hreg[i * 4 + 1], a0);
                    a0 = fmaf(cur[i].z, hreg[i * 4 + 2], a0);
                    a0 = fmaf(cur[i].w, hreg[i * 4 + 3], a0);
                }
                a0 += __shfl_xor(a0, 1); a0 += __shfl_xor(a0, 2); a0 += __shfl_xor(a0, 4);
                if (oct == 0) hgp[q * 64 + ajg] = a0;
            };
#pragma unroll 1
            for (int q = 0; q < 8; q += 2) { p3(wA, wB, q); p3(wB, wA, q + 1); }
        } else {
            wround(0); wround(1); wround(2); wround(3);
        }
        __syncthreads();
        // ---- seg1: attn gs (rep loop); weight rounds 4-6 ----
        if (tid < 512) {
            const int uc = ucount_s;
#pragma unroll 1
            for (int rep = 0; rep < 2; ++rep) {
                const int k = ajg + rep * 64;
                if (k < uc) {
                    const int r = ulist[k];
                    const float* gr = &grefb[(size_t)r * 256 + oct * 4];
                    f32x4 g0[8];
#pragma unroll
                    for (int i = 0; i < 8; ++i) g0[i] = ld4(gr + i * 32);
                    float part = 0.0f;
#pragma unroll
                    for (int i = 0; i < 8; ++i) {
                        const int d = i * 32 + oct * 4;
                        const f32x4 hh = ld4(&hgp[d]);
                        const f32x4 vv = ld4(&gv_lds[d]);
                        part = fmaf(ftanh_fast(g0[i].x + hh.x), vv.x, part);
                        part = fmaf(ftanh_fast(g0[i].y + hh.y), vv.y, part);
                        part = fmaf(ftanh_fast(g0[i].z + hh.z), vv.z, part);
                        part = fmaf(ftanh_fast(g0[i].w + hh.w), vv.w, part);
                    }
                    part += __shfl_xor(part, 1); part += __shfl_xor(part, 2); part += __shfl_xor(part, 4);
                    if (oct == 0) sc_arr[r] = part * 0.0625f;
                }
            }
        } else {
            wround(4); wround(5); wround(6);
        }
        __syncthreads();
        // ---- segC: attn ctx with inline wave softmax; weight rounds 7-9 ----
        if (tid < 512) {
            float s0 = sc_arr[lane], s1 = sc_arr[lane + 64];
            float m = fmaxf(s0, s1);
#pragma unroll
            for (int mk = 1; mk < 64; mk <<= 1) m = fmaxf(m, __shfl_xor(m, mk));
            float e0 = expf(s0 - m), e1 = expf(s1 - m);
            float z = e0 + e1;
#pragma unroll
            for (int mk = 1; mk < 64; mk <<= 1) z += __shfl_xor(z, mk);
            if (tid == 0) Z_s = z;
            const int uc = ucount_s;
            const int d4 = lane * 4;
            float ax = 0.0f, ay = 0.0f, az = 0.0f, aw = 0.0f;
            if (wid * 16 < uc) {
#pragma unroll 1
                for (int half = 0; half < 2; ++half) {
                    const int k0 = wid * 16 + half * 8;
                    if (k0 < uc) {
                        f32x4 p0[8]; float ee[8];
#pragma unroll
                        for (int i = 0; i < 8; ++i) {
                            const int k = k0 + i;
                            const int kc = (k < uc) ? k : (uc - 1);
                            const int s = ulist[kc];
                            ee[i] = (k < uc) ? expf(sc_arr[s] - m) : 0.0f;
                            p0[i] = ld4(&encPb[(size_t)s * 256 + d4]);
                        }
#pragma unroll
                        for (int i = 0; i < 8; ++i) {
                            ax = fmaf(p0[i].x, ee[i], ax); ay = fmaf(p0[i].y, ee[i], ay);
                            az = fmaf(p0[i].z, ee[i], az); aw = fmaf(p0[i].w, ee[i], aw);
                        }
                    }
                }
            }
            *reinterpret_cast<float4*>(&hp_half[wid][d4]) = make_float4(ax, ay, az, aw);
        } else {
            wround(7); wround(8); wround(9);
        }
        __syncthreads();
        // ---- seg4: hp combine (256 thr); weight rounds 10-12 ----
        if (tid < 256) {
            float s = 0.0f;
#pragma unroll
            for (int k = 0; k < 8; ++k) s += hp_half[k][tid];
            hp_lds[tid] = hgp[256 + tid] + s * frcp(Z_s);
        } else if (tid >= 512) {
            wround(10); wround(11); wround(12);
        }
        __syncthreads();
        // ---- seg5: attn ps (rep loop, hp_lds); weight rounds 13-15 ----
        if (tid < 512) {
            const int uc = ucount_s;
#pragma unroll 1
            for (int rep = 0; rep < 2; ++rep) {
                const int k = ajg + rep * 64;
                if (k < uc) {
                    const int r = ulist[k];
                    const float* pr = &prefb[(size_t)r * 256 + oct * 4];
                    f32x4 g0[8];
#pragma unroll
                    for (int i = 0; i < 8; ++i) g0[i] = ld4(pr + i * 32);
                    float part = 0.0f;
#pragma unroll
                    for (int i = 0; i < 8; ++i) {
                        const int d = i * 32 + oct * 4;
                        const f32x4 hh = ld4(&hp_lds[d]);
                        const f32x4 vv = ld4(&pv_lds[d]);
                        part = fmaf(ftanh_fast(g0[i].x + hh.x), vv.x, part);
                        part = fmaf(ftanh_fast(g0[i].y + hh.y), vv.y, part);
                        part = fmaf(ftanh_fast(g0[i].z + hh.z), vv.z, part);
                        part = fmaf(ftanh_fast(g0[i].w + hh.w), vv.w, part);
                    }
                    part += __shfl_xor(part, 1); part += __shfl_xor(part, 2); part += __shfl_xor(part, 4);
                    if (oct == 0) sc_arr[r] = part * 0.0625f;
                }
            }
        } else {
            wround(13); wround(14); wround(15);
        }
        __syncthreads();
        // ---- segA: logits + argmax (first-max semantics) ----
        if (tid < 128) {
            out_logits[((size_t)(b * SS + t)) * SS + tid] = sc_arr[tid];
        }
        if (tid < 64) {
            float v = sc_arr[lane];
            int idx = lane;
            float v2 = sc_arr[lane + 64];
            if (v2 > v) { v = v2; idx = lane + 64; }
#pragma unroll
            for (int mk = 1; mk < 64; mk <<= 1) {
                float ov = __shfl_xor(v, mk);
                int oi = __shfl_xor(idx, mk);
                if (ov > v || (ov == v && oi < idx)) { v = ov; idx = oi; }
            }
            if (lane == 0) {
                sel_s = idx;
                mask_lds[idx] = 1;
                out_ptrs[(size_t)b * SS + t] = (float)idx;
            }
        }
        __syncthreads();
    }
}

// =====================================================================
// host launcher
// =====================================================================
extern "C" void kernel_launch(void* const* d_in, const int* in_sizes, int n_in,
                              void* d_out, int out_size, void* d_ws, size_t ws_size,
                              hipStream_t stream)
{
    (void)in_sizes; (void)n_in; (void)out_size; (void)ws_size;
    const float* x      = (const float*)d_in[0];
    const float* proj_W = (const float*)d_in[1];
    const float* proj_b = (const float*)d_in[2];
    const float* ln_g   = (const float*)d_in[3];
    const float* ln_b   = (const float*)d_in[4];
    const float* Wih_f  = (const float*)d_in[5];
    const float* Whh_f  = (const float*)d_in[6];
    const float* bih_f  = (const float*)d_in[7];
    const float* bhh_f  = (const float*)d_in[8];
    const float* Wih_b  = (const float*)d_in[9];
    const float* Whh_b  = (const float*)d_in[10];
    const float* bih_b  = (const float*)d_in[11];
    const float* bhh_b  = (const float*)d_in[12];
    const float* Wih_d  = (const float*)d_in[13];
    const float* Whh_d  = (const float*)d_in[14];
    const float* bih_d  = (const float*)d_in[15];
    const float* bhh_d  = (const float*)d_in[16];
    const float* hb_W   = (const float*)d_in[17];
    const float* hb_b   = (const float*)d_in[18];
    const float* cb_W   = (const float*)d_in[19];
    const float* cb_b   = (const float*)d_in[20];
    const float* gW1    = (const float*)d_in[21];
    const float* gW2    = (const float*)d_in[22];
    const float* gv     = (const float*)d_in[23];
    const float* pW1    = (const float*)d_in[24];
    const float* pW2    = (const float*)d_in[25];
    const float* pv     = (const float*)d_in[26];

    float* ws = (float*)d_ws;
    const size_t o_hT    = 0;
    const size_t o_cT    = 65536;
    const size_t o_h0    = 131072;
    const size_t o_c0    = 163840;
    const size_t o_pre0  = 196608;
    const size_t o_emb   = 0;
    const size_t o_xf    = 4194304;
    const size_t o_xb    = o_xf + 16777216;
    const size_t o_enc   = o_xb + 16777216;
    const size_t o_encW  = o_xf;
    const size_t o_gref  = o_xb;
    const size_t o_pref  = o_xb + 4194304;
    const size_t o_encP  = o_xb + 8388608;

    float* emb  = ws + o_emb;
    float* xf   = ws + o_xf;
    float* xb   = ws + o_xb;
    float* enc  = ws + o_enc;
    float* hT   = ws + o_hT;
    float* cT   = ws + o_cT;
    float* h0b  = ws + o_h0;
    float* c0b  = ws + o_c0;
    float* pre0 = ws + o_pre0;
    float* encW = ws + o_encW;
    float* gref = ws + o_gref;
    float* pref = ws + o_pref;
    float* encP = ws + o_encP;

    float* out_logits = (float*)d_out;
    float* out_ptrs   = out_logits + (size_t)BB * SS * SS;

    // 1. emb
    k_proj_ln<<<BB * SS, 256, 0, stream>>>(x, proj_W, proj_b, ln_g, ln_b, emb);
    // 2-3. xf / xb  (bias = bih + bhh)
    {
        dim3 g(128, 8);
        k_gemm_nt<<<g, 256, 0, stream>>>(emb, 256, Wih_f, xf, 16384, 1024, 256, bih_f, bhh_f, 0);
        k_gemm_nt<<<g, 256, 0, stream>>>(emb, 256, Wih_b, xb, 16384, 1024, 256, bih_b, bhh_b, 0);
    }
    // 4. LSTM both directions: 256 WGs x 512 threads (R12 proven)
    k_lstm<<<256, 512, 0, stream>>>(Whh_f, Whh_b, xf, xb, enc, hT, cT);
    // 5-6. h0 / c0
    {
        dim3 g(1, 2);
        k_gemm_nt<<<g, 256, 0, stream>>>(hT, 512, hb_W, h0b, 128, 256, 512, hb_b, nullptr, 1);
        k_gemm_nt<<<g, 256, 0, stream>>>(cT, 512, cb_W, c0b, 128, 256, 512, cb_b, nullptr, 1);
    }
    // 7-10. attention precomputes
    {
        dim3 g2(128, 2);
        k_gemm_nt<<<g2, 256, 0, stream>>>(enc, 512, gW1, gref, 16384, 256, 512, nullptr, nullptr, 0);
        k_gemm_nt<<<g2, 256, 0, stream>>>(enc, 512, pW1, pref, 16384, 256, 512, nullptr, nullptr, 0);
        dim3 g1(128, 8);
        k_gemm_nt<<<g1, 256, 0, stream>>>(enc, 512, Wih_d, encW, 16384, 1024, 512, bih_d, bhh_d, 0);
        k_gemm_nt<<<g2, 256, 0, stream>>>(enc, 512, pW2, encP, 16384, 256, 256, nullptr, nullptr, 0);
    }
    // 11. pre0 = mean_s encW
    k_meanw<<<BB, 256, 0, stream>>>(encW, pre0);
    // 12. decoder: 128 WGs x 1024 threads, wave-specialized, 7 barriers/step
    k_decoder<<<128, 1024, 0, stream>>>(Whh_d, gW2, pW2, gv, pv, gref, pref, encP, encW,
                                        pre0, h0b, c0b, out_logits, out_ptrs);
}

// Round 18
// 5109.456 us; speedup vs baseline: 1.0648x; 1.0648x over previous
//
#include <hip/hip_runtime.h>
#include <cstdint>
#include <cstddef>

#define DEVINL __device__ __forceinline__

typedef float f32x4 __attribute__((ext_vector_type(4)));

DEVINL float ntload1(const float* p) {
    return __builtin_nontemporal_load(p);
}
DEVINL f32x4 ld4(const float* p) {
    return *reinterpret_cast<const f32x4*>(p);
}

// ---------- math helpers ----------
DEVINL float frcp(float x) { return __builtin_amdgcn_rcpf(x); }
DEVINL float ftanh_fast(float x) {
    float e = __expf(2.0f * x);
    return 1.0f - 2.0f * frcp(e + 1.0f);
}
DEVINL float sig_precise(float x) { return 1.0f / (1.0f + expf(-x)); }
DEVINL float tanh_precise(float x) { return tanhf(x); }

// ---------- sizes ----------
#define BB 128
#define SS 128
#define IND 16
#define DD 256
#define HH 256
#define H4 1024
#define H2 512

// =====================================================================
// K1: emb = LayerNorm(tanh(x @ proj_W.T + proj_b))   (one block per row)
// =====================================================================
__global__ __launch_bounds__(256) void k_proj_ln(
    const float* __restrict__ x, const float* __restrict__ projW,
    const float* __restrict__ projB, const float* __restrict__ ln_g,
    const float* __restrict__ ln_b, float* __restrict__ emb)
{
    __shared__ float Wl[256 * 17];
    __shared__ float xl[16];
    __shared__ float red[256];
    const int row = blockIdx.x;
    const int tid = threadIdx.x;
    for (int idx = tid; idx < 256 * 16; idx += 256) {
        int d = idx >> 4, i = idx & 15;
        Wl[d * 17 + i] = projW[idx];
    }
    if (tid < 16) xl[tid] = x[row * 16 + tid];
    __syncthreads();
    float acc = projB[tid];
#pragma unroll
    for (int i = 0; i < 16; ++i) acc = fmaf(Wl[tid * 17 + i], xl[i], acc);
    float v = tanh_precise(acc);
    red[tid] = v;
    __syncthreads();
    for (int s2 = 128; s2 > 0; s2 >>= 1) { if (tid < s2) red[tid] += red[tid + s2]; __syncthreads(); }
    float mean = red[0] * (1.0f / 256.0f);
    __syncthreads();
    float dlt = v - mean;
    red[tid] = dlt * dlt;
    __syncthreads();
    for (int s2 = 128; s2 > 0; s2 >>= 1) { if (tid < s2) red[tid] += red[tid + s2]; __syncthreads(); }
    float var = red[0] * (1.0f / 256.0f);
    float rs = 1.0f / sqrtf(var + 1e-5f);
    emb[(size_t)row * 256 + tid] = dlt * rs * ln_g[tid] + ln_b[tid];
}

// =====================================================================
// K2: generic fp32 GEMM-NT  C(MxN) = A(MxK,lda) * B(NxK)^T (+bias1+bias2)
// single-buffered (R16 proven: 16.9 KB LDS -> ~8 WGs/CU occupancy)
// =====================================================================
__global__ __launch_bounds__(256) void k_gemm_nt(
    const float* __restrict__ A, int lda,
    const float* __restrict__ Bm,
    float* __restrict__ C,
    int M, int N, int K,
    const float* __restrict__ bias1, const float* __restrict__ bias2,
    int flags)
{
    __shared__ __align__(16) float As[16][132];
    __shared__ __align__(16) float Bs[16][132];
    const int tid = threadIdx.x;
    const int m0 = blockIdx.x * 128;
    const int n0 = blockIdx.y * 128;
    const int r = tid >> 1, half = tid & 1;
    const int tm = tid & 15, tn = tid >> 4;
    float acc[8][8];
#pragma unroll
    for (int i = 0; i < 8; ++i)
#pragma unroll
        for (int j = 0; j < 8; ++j) acc[i][j] = 0.0f;

    for (int k0 = 0; k0 < K; k0 += 16) {
        const float4* pa = reinterpret_cast<const float4*>(&A[(size_t)(m0 + r) * lda + k0 + half * 8]);
        float4 a0 = pa[0], a1 = pa[1];
        const float4* pb = reinterpret_cast<const float4*>(&Bm[(size_t)(n0 + r) * K + k0 + half * 8]);
        float4 b0 = pb[0], b1 = pb[1];
        __syncthreads();
        const int kb = half * 8;
        As[kb + 0][r] = a0.x; As[kb + 1][r] = a0.y; As[kb + 2][r] = a0.z; As[kb + 3][r] = a0.w;
        As[kb + 4][r] = a1.x; As[kb + 5][r] = a1.y; As[kb + 6][r] = a1.z; As[kb + 7][r] = a1.w;
        Bs[kb + 0][r] = b0.x; Bs[kb + 1][r] = b0.y; Bs[kb + 2][r] = b0.z; Bs[kb + 3][r] = b0.w;
        Bs[kb + 4][r] = b1.x; Bs[kb + 5][r] = b1.y; Bs[kb + 6][r] = b1.z; Bs[kb + 7][r] = b1.w;
        __syncthreads();
#pragma unroll
        for (int kk = 0; kk < 16; ++kk) {
            const float4 xa0 = *reinterpret_cast<const float4*>(&As[kk][tm * 8]);
            const float4 xa1 = *reinterpret_cast<const float4*>(&As[kk][tm * 8 + 4]);
            const float4 xb0 = *reinterpret_cast<const float4*>(&Bs[kk][tn * 8]);
            const float4 xb1 = *reinterpret_cast<const float4*>(&Bs[kk][tn * 8 + 4]);
            const float av[8] = {xa0.x, xa0.y, xa0.z, xa0.w, xa1.x, xa1.y, xa1.z, xa1.w};
            const float bv[8] = {xb0.x, xb0.y, xb0.z, xb0.w, xb1.x, xb1.y, xb1.z, xb1.w};
#pragma unroll
            for (int i = 0; i < 8; ++i)
#pragma unroll
                for (int j = 0; j < 8; ++j) acc[i][j] = fmaf(av[i], bv[j], acc[i][j]);
        }
    }
    const int nb = n0 + tn * 8;
    float bias[8];
#pragma unroll
    for (int j = 0; j < 8; ++j) {
        float bbv = 0.0f;
        if (bias1) bbv += bias1[nb + j];
        if (bias2) bbv += bias2[nb + j];
        bias[j] = bbv;
    }
#pragma unroll
    for (int i = 0; i < 8; ++i) {
        const size_t m = (size_t)(m0 + tm * 8 + i);
        float o[8];
#pragma unroll
        for (int j = 0; j < 8; ++j) {
            float vv = acc[i][j] + bias[j];
            if (flags & 1) vv = tanh_precise(vv);
            o[j] = vv;
        }
        float4* pc = reinterpret_cast<float4*>(&C[m * N + nb]);
        pc[0] = make_float4(o[0], o[1], o[2], o[3]);
        pc[1] = make_float4(o[4], o[5], o[6], o[7]);
    }
}

// =====================================================================
// K3: bidirectional LSTM (R12 proven): 256 WGs x 512 threads, ONE chain
// per WG. Compact dbuf W-pass (16 rounds of 64 rows).
// =====================================================================
__global__ __launch_bounds__(512, 2) void k_lstm(
    const float* __restrict__ Whh_f, const float* __restrict__ Whh_b,
    const float* __restrict__ xf, const float* __restrict__ xb,
    float* __restrict__ enc, float* __restrict__ hT, float* __restrict__ cT)
{
    const int wg = blockIdx.x;       // 0..255
    const int dir = wg >> 7;
    const int bat = wg & 127;
    const float* W = dir ? Whh_b : Whh_f;
    const float* xin = dir ? xb : xf;
    const int tid = threadIdx.x;
    const int oct = tid & 7, jg = tid >> 3;   // jg 0..63

    __shared__ __align__(16) float h_lds[256];
    __shared__ float pre_lds[1024];

    if (tid < 256) h_lds[tid] = 0.0f;
    float c_reg = 0.0f;
    __syncthreads();

    for (int t = 0; t < SS; ++t) {
        const int st = dir ? (SS - 1 - t) : t;
        float hreg[32];
#pragma unroll
        for (int i = 0; i < 8; ++i) {
            f32x4 v = ld4(&h_lds[i * 32 + oct * 4]);
            hreg[i * 4 + 0] = v.x; hreg[i * 4 + 1] = v.y;
            hreg[i * 4 + 2] = v.z; hreg[i * 4 + 3] = v.w;
        }
        {
            f32x4 wA[8], wB[8];
            {
                const float* bp = &W[(size_t)jg * 256 + oct * 4];
#pragma unroll
                for (int i = 0; i < 8; ++i) wA[i] = ld4(bp + i * 32);
            }
            auto wstep = [&](f32x4 (&cur)[8], f32x4 (&nxt)[8], int q) {
                if (q < 15) {
                    const float* bp = &W[(size_t)((q + 1) * 64 + jg) * 256 + oct * 4];
#pragma unroll
                    for (int i = 0; i < 8; ++i) nxt[i] = ld4(bp + i * 32);
                }
                float a0 = 0.0f;
#pragma unroll
                for (int i = 0; i < 8; ++i) {
                    a0 = fmaf(cur[i].x, hreg[i * 4 + 0], a0);
                    a0 = fmaf(cur[i].y, hreg[i * 4 + 1], a0);
                    a0 = fmaf(cur[i].z, hreg[i * 4 + 2], a0);
                    a0 = fmaf(cur[i].w, hreg[i * 4 + 3], a0);
                }
                a0 += __shfl_xor(a0, 1); a0 += __shfl_xor(a0, 2); a0 += __shfl_xor(a0, 4);
                if (oct == 0) pre_lds[q * 64 + jg] = a0;
            };
#pragma unroll 1
            for (int q = 0; q < 16; q += 2) { wstep(wA, wB, q); wstep(wB, wA, q + 1); }
        }
        __syncthreads();
        if (tid < 256) {
            const int gc = tid;
            const float* xrow = &xin[((size_t)bat * SS + st) * 1024];
            float pi = pre_lds[gc]       + ntload1(&xrow[gc]);
            float pf = pre_lds[256 + gc] + ntload1(&xrow[256 + gc]);
            float pg = pre_lds[512 + gc] + ntload1(&xrow[512 + gc]);
            float po = pre_lds[768 + gc] + ntload1(&xrow[768 + gc]);
            float ig = sig_precise(pi), fg = sig_precise(pf);
            float gg = tanh_precise(pg), og = sig_precise(po);
            float cn = fmaf(fg, c_reg, ig * gg);
            float hn = og * tanh_precise(cn);
            c_reg = cn;
            h_lds[gc] = hn;
            enc[((size_t)bat * SS + st) * 512 + dir * 256 + gc] = hn;
            if (t == SS - 1) {
                hT[(size_t)bat * 512 + dir * 256 + gc] = hn;
                cT[(size_t)bat * 512 + dir * 256 + gc] = cn;
            }
        }
        __syncthreads();
    }
}

// =====================================================================
// K5: pre0[b][j] = mean_s encW[b][s][j]
// =====================================================================
__global__ __launch_bounds__(256) void k_meanw(const float* __restrict__ encW, float* __restrict__ pre0)
{
    const int b = blockIdx.x;
    const int tid = threadIdx.x;
    const float4* base = reinterpret_cast<const float4*>(&encW[(size_t)b * SS * 1024]);
    float sx = 0.0f, sy = 0.0f, sz = 0.0f, sw = 0.0f;
    for (int s = 0; s < SS; ++s) {
        float4 v = base[s * 256 + tid];
        sx += v.x; sy += v.y; sz += v.z; sw += v.w;
    }
    float4* out = reinterpret_cast<float4*>(&pre0[(size_t)b * 1024]);
    out[tid] = make_float4(sx * (1.0f / 128.0f), sy * (1.0f / 128.0f), sz * (1.0f / 128.0f), sw * (1.0f / 128.0f));
}

// =====================================================================
// K6: pointer decoder (R16 verbatim): 128 WGs x 1024 threads,
// wave-specialized, 7 barriers/step.
// =====================================================================
__global__ __launch_bounds__(1024) void k_decoder(
    const float* __restrict__ Whh_d,
    const float* __restrict__ gW2, const float* __restrict__ pW2,
    const float* __restrict__ gv, const float* __restrict__ pv,
    const float* __restrict__ g_ref, const float* __restrict__ p_ref,
    const float* __restrict__ encP, const float* __restrict__ encW,
    const float* __restrict__ pre0, const float* __restrict__ h0,
    const float* __restrict__ c0,
    float* __restrict__ out_logits, float* __restrict__ out_ptrs)
{
    const int b = blockIdx.x;             // batch
    const int tid = threadIdx.x;
    const int oct = tid & 7;
    const int jg128 = tid >> 3;           // 0..127 (prologue)
    const int wid = tid >> 6, lane = tid & 63;
    const int ajg = (tid & 511) >> 3;     // 0..63 (both sides)

    __shared__ __align__(16) float h_lds[256];
    __shared__ float c_lds[256];
    __shared__ float wacc_lds[1024];
    __shared__ __align__(16) float hgp[512];   // [0..255]=hg, [256..511]=hp1
    __shared__ __align__(16) float hp_lds[256];
    __shared__ __align__(16) float gv_lds[256];
    __shared__ __align__(16) float pv_lds[256];
    __shared__ float sc_arr[128];
    __shared__ __align__(16) float hp_half[8][256];
    __shared__ int mask_lds[128];
    __shared__ int ulist[128];
    __shared__ int ucount_s;
    __shared__ float Z_s;
    __shared__ int sel_s;

    if (tid < 256) {
        gv_lds[tid] = gv[tid];
        pv_lds[tid] = pv[tid];
        h_lds[tid] = h0[(size_t)b * 256 + tid];
        c_lds[tid] = c0[(size_t)b * 256 + tid];
    }
    if (tid < 128) mask_lds[tid] = 0;
    if (tid == 0) sel_s = -1;
    const float* grefb = g_ref + (size_t)b * SS * 256;
    const float* prefb = p_ref + (size_t)b * SS * 256;
    const float* encPb = encP + (size_t)b * SS * 256;
    const float* pre0b = pre0 + (size_t)b * 1024;
    const float* encWb = encW + (size_t)b * SS * 1024;
    __syncthreads();

    // ---- prologue: wacc = Whh_d @ h0 (all waves; 8 rounds of 128 rows) ----
    {
        float hreg0[32];
#pragma unroll
        for (int i = 0; i < 8; ++i) {
            f32x4 v = ld4(&h_lds[i * 32 + oct * 4]);
            hreg0[i * 4 + 0] = v.x; hreg0[i * 4 + 1] = v.y;
            hreg0[i * 4 + 2] = v.z; hreg0[i * 4 + 3] = v.w;
        }
        f32x4 wA[8], wB[8];
        {
            const float* bp = &Whh_d[(size_t)jg128 * 256 + oct * 4];
#pragma unroll
            for (int i = 0; i < 8; ++i) wA[i] = ld4(bp + i * 32);
        }
        auto pw = [&](f32x4 (&cur)[8], f32x4 (&nxt)[8], int q) {
            if (q < 7) {
                const float* bp = &Whh_d[(size_t)((q + 1) * 128 + jg128) * 256 + oct * 4];
#pragma unroll
                for (int i = 0; i < 8; ++i) nxt[i] = ld4(bp + i * 32);
            }
            float a0 = 0.0f;
#pragma unroll
            for (int i = 0; i < 8; ++i) {
                a0 = fmaf(cur[i].x, hreg0[i * 4 + 0], a0);
                a0 = fmaf(cur[i].y, hreg0[i * 4 + 1], a0);
                a0 = fmaf(cur[i].z, hreg0[i * 4 + 2], a0);
                a0 = fmaf(cur[i].w, hreg0[i * 4 + 3], a0);
            }
            a0 += __shfl_xor(a0, 1); a0 += __shfl_xor(a0, 2); a0 += __shfl_xor(a0, 4);
            if (oct == 0) wacc_lds[q * 128 + jg128] = a0;
        };
#pragma unroll 1
        for (int q = 0; q < 8; q += 2) { pw(wA, wB, q); pw(wB, wA, q + 1); }
    }
    __syncthreads();

    for (int t = 0; t < SS; ++t) {
        // ---- segG: gates (direct row loads) | ulist (wave 8) | sc init ----
        if (tid < 256) {
            const int ch = tid;
            const int sel = sel_s;
            const float* src = (sel < 0) ? pre0b : &encWb[(size_t)sel * 1024];
            float r0 = src[ch], r1 = src[256 + ch], r2 = src[512 + ch], r3 = src[768 + ch];
            float pi = wacc_lds[ch]       + r0;
            float pf = wacc_lds[256 + ch] + r1;
            float pg = wacc_lds[512 + ch] + r2;
            float po = wacc_lds[768 + ch] + r3;
            float ig = sig_precise(pi), fg = sig_precise(pf);
            float gg = tanh_precise(pg), og = sig_precise(po);
            float cn = fmaf(fg, c_lds[ch], ig * gg);
            float hn = og * tanh_precise(cn);
            c_lds[ch] = cn;
            h_lds[ch] = hn;
        } else if (tid < 384) {
            sc_arr[tid - 256] = -1e9f;
        } else if (tid >= 512 && tid < 576) {
            const unsigned long long lowmask = (1ull << lane) - 1ull;
            const bool u0 = (mask_lds[lane] == 0);
            const unsigned long long b0m = __ballot(u0);
            if (u0) ulist[__popcll(b0m & lowmask)] = lane;
            const bool u1 = (mask_lds[lane + 64] == 0);
            const unsigned long long b1m = __ballot(u1);
            const int c0 = __popcll(b0m);
            if (u1) ulist[c0 + __popcll(b1m & lowmask)] = lane + 64;
            if (lane == 0) ucount_s = c0 + __popcll(b1m);
        }
        __syncthreads();
        // h_t -> regs (both sides)
        float hreg[32];
#pragma unroll
        for (int i = 0; i < 8; ++i) {
            f32x4 v = ld4(&h_lds[i * 32 + oct * 4]);
            hreg[i * 4 + 0] = v.x; hreg[i * 4 + 1] = v.y;
            hreg[i * 4 + 2] = v.z; hreg[i * 4 + 3] = v.w;
        }
        // weight-side round: wacc(t+1)[q*64+ajg] = Whh_d row @ h_t
        auto wround = [&](int q) {
            const float* bp = &Whh_d[(size_t)(q * 64 + ajg) * 256 + oct * 4];
            f32x4 w[8];
#pragma unroll
            for (int i = 0; i < 8; ++i) w[i] = ld4(bp + i * 32);
            float a0 = 0.0f;
#pragma unroll
            for (int i = 0; i < 8; ++i) {
                a0 = fmaf(w[i].x, hreg[i * 4 + 0], a0);
                a0 = fmaf(w[i].y, hreg[i * 4 + 1], a0);
                a0 = fmaf(w[i].z, hreg[i * 4 + 2], a0);
                a0 = fmaf(w[i].w, hreg[i * 4 + 3], a0);
            }
            a0 += __shfl_xor(a0, 1); a0 += __shfl_xor(a0, 2); a0 += __shfl_xor(a0, 4);
            if (oct == 0) wacc_lds[q * 64 + ajg] = a0;
        };
        // ---- seg0: attn hgp (8 dbuf rounds); weight rounds 0-3 ----
        if (tid < 512) {
            f32x4 wA[8], wB[8];
            {
                const float* src0 = (ajg < 256) ? &gW2[(size_t)ajg * 256] : &pW2[(size_t)(ajg - 256) * 256];
#pragma unroll
                for (int i = 0; i < 8; ++i) wA[i] = ld4(src0 + oct * 4 + i * 32);
            }
            auto p3 = [&](f32x4 (&cur)[8], f32x4 (&nxt)[8], int q) {
                if (q < 7) {
                    const int r2 = (q + 1) * 64 + ajg;
                    const float* src = (r2 < 256) ? &gW2[(size_t)r2 * 256] : &pW2[(size_t)(r2 - 256) * 256];
#pragma unroll
                    for (int i = 0; i < 8; ++i) nxt[i] = ld4(src + oct * 4 + i * 32);
                }
                float a0 = 0.0f;
#pragma unroll
                for (int i = 0; i < 8; ++i) {
                    a0 = fmaf(cur[i].x, hreg[i * 4 + 0], a0);
                    a0 = fmaf(cur[i].y, hreg[i * 4 + 1], a0);
                    a0 = fmaf(cur[i].z, hreg[i * 4 + 2], a0);
                    a0 = fmaf(cur[i].w, hreg[i * 4 + 3], a0);
                }
                a0 += __shfl_xor(a0, 1); a0 += __shfl_xor(a0, 2); a0 += __shfl_xor(a0, 4);
                if (oct == 0) hgp[q * 64 + ajg] = a0;
            };
#pragma unroll 1
            for (int q = 0; q < 8; q += 2) { p3(wA, wB, q); p3(wB, wA, q + 1); }
        } else {
            wround(0); wround(1); wround(2); wround(3);
        }
        __syncthreads();
        // ---- seg1: attn gs (rep loop); weight rounds 4-6 ----
        if (tid < 512) {
            const int uc = ucount_s;
#pragma unroll 1
            for (int rep = 0; rep < 2; ++rep) {
                const int k = ajg + rep * 64;
                if (k < uc) {
                    const int r = ulist[k];
                    const float* gr = &grefb[(size_t)r * 256 + oct * 4];
                    f32x4 g0[8];
#pragma unroll
                    for (int i = 0; i < 8; ++i) g0[i] = ld4(gr + i * 32);
                    float part = 0.0f;
#pragma unroll
                    for (int i = 0; i < 8; ++i) {
                        const int d = i * 32 + oct * 4;
                        const f32x4 hh = ld4(&hgp[d]);
                        const f32x4 vv = ld4(&gv_lds[d]);
                        part = fmaf(ftanh_fast(g0[i].x + hh.x), vv.x, part);
                        part = fmaf(ftanh_fast(g0[i].y + hh.y), vv.y, part);
                        part = fmaf(ftanh_fast(g0[i].z + hh.z), vv.z, part);
                        part = fmaf(ftanh_fast(g0[i].w + hh.w), vv.w, part);
                    }
                    part += __shfl_xor(part, 1); part += __shfl_xor(part, 2); part += __shfl_xor(part, 4);
                    if (oct == 0) sc_arr[r] = part * 0.0625f;
                }
            }
        } else {
            wround(4); wround(5); wround(6);
        }
        __syncthreads();
        // ---- segC: attn ctx with inline wave softmax; weight rounds 7-9 ----
        if (tid < 512) {
            float s0 = sc_arr[lane], s1 = sc_arr[lane + 64];
            float m = fmaxf(s0, s1);
#pragma unroll
            for (int mk = 1; mk < 64; mk <<= 1) m = fmaxf(m, __shfl_xor(m, mk));
            float e0 = expf(s0 - m), e1 = expf(s1 - m);
            float z = e0 + e1;
#pragma unroll
            for (int mk = 1; mk < 64; mk <<= 1) z += __shfl_xor(z, mk);
            if (tid == 0) Z_s = z;
            const int uc = ucount_s;
            const int d4 = lane * 4;
            float ax = 0.0f, ay = 0.0f, az = 0.0f, aw = 0.0f;
            if (wid * 16 < uc) {
#pragma unroll 1
                for (int half = 0; half < 2; ++half) {
                    const int k0 = wid * 16 + half * 8;
                    if (k0 < uc) {
                        f32x4 p0[8]; float ee[8];
#pragma unroll
                        for (int i = 0; i < 8; ++i) {
                            const int k = k0 + i;
                            const int kc = (k < uc) ? k : (uc - 1);
                            const int s = ulist[kc];
                            ee[i] = (k < uc) ? expf(sc_arr[s] - m) : 0.0f;
                            p0[i] = ld4(&encPb[(size_t)s * 256 + d4]);
                        }
#pragma unroll
                        for (int i = 0; i < 8; ++i) {
                            ax = fmaf(p0[i].x, ee[i], ax); ay = fmaf(p0[i].y, ee[i], ay);
                            az = fmaf(p0[i].z, ee[i], az); aw = fmaf(p0[i].w, ee[i], aw);
                        }
                    }
                }
            }
            *reinterpret_cast<float4*>(&hp_half[wid][d4]) = make_float4(ax, ay, az, aw);
        } else {
            wround(7); wround(8); wround(9);
        }
        __syncthreads();
        // ---- seg4: hp combine (256 thr); weight rounds 10-12 ----
        if (tid < 256) {
            float s = 0.0f;
#pragma unroll
            for (int k = 0; k < 8; ++k) s += hp_half[k][tid];
            hp_lds[tid] = hgp[256 + tid] + s * frcp(Z_s);
        } else if (tid >= 512) {
            wround(10); wround(11); wround(12);
        }
        __syncthreads();
        // ---- seg5: attn ps (rep loop, hp_lds); weight rounds 13-15 ----
        if (tid < 512) {
            const int uc = ucount_s;
#pragma unroll 1
            for (int rep = 0; rep < 2; ++rep) {
                const int k = ajg + rep * 64;
                if (k < uc) {
                    const int r = ulist[k];
                    const float* pr = &prefb[(size_t)r * 256 + oct * 4];
                    f32x4 g0[8];
#pragma unroll
                    for (int i = 0; i < 8; ++i) g0[i] = ld4(pr + i * 32);
                    float part = 0.0f;
#pragma unroll
                    for (int i = 0; i < 8; ++i) {
                        const int d = i * 32 + oct * 4;
                        const f32x4 hh = ld4(&hp_lds[d]);
                        const f32x4 vv = ld4(&pv_lds[d]);
                        part = fmaf(ftanh_fast(g0[i].x + hh.x), vv.x, part);
                        part = fmaf(ftanh_fast(g0[i].y + hh.y), vv.y, part);
                        part = fmaf(ftanh_fast(g0[i].z + hh.z), vv.z, part);
                        part = fmaf(ftanh_fast(g0[i].w + hh.w), vv.w, part);
                    }
                    part += __shfl_xor(part, 1); part += __shfl_xor(part, 2); part += __shfl_xor(part, 4);
                    if (oct == 0) sc_arr[r] = part * 0.0625f;
                }
            }
        } else {
            wround(13); wround(14); wround(15);
        }
        __syncthreads();
        // ---- segA: logits + argmax (first-max semantics) ----
        if (tid < 128) {
            out_logits[((size_t)(b * SS + t)) * SS + tid] = sc_arr[tid];
        }
        if (tid < 64) {
            float v = sc_arr[lane];
            int idx = lane;
            float v2 = sc_arr[lane + 64];
            if (v2 > v) { v = v2; idx = lane + 64; }
#pragma unroll
            for (int mk = 1; mk < 64; mk <<= 1) {
                float ov = __shfl_xor(v, mk);
                int oi = __shfl_xor(idx, mk);
                if (ov > v || (ov == v && oi < idx)) { v = ov; idx = oi; }
            }
            if (lane == 0) {
                sel_s = idx;
                mask_lds[idx] = 1;
                out_ptrs[(size_t)b * SS + t] = (float)idx;
            }
        }
        __syncthreads();
    }
}

// =====================================================================
// host launcher
// =====================================================================
extern "C" void kernel_launch(void* const* d_in, const int* in_sizes, int n_in,
                              void* d_out, int out_size, void* d_ws, size_t ws_size,
                              hipStream_t stream)
{
    (void)in_sizes; (void)n_in; (void)out_size; (void)ws_size;
    const float* x      = (const float*)d_in[0];
    const float* proj_W = (const float*)d_in[1];
    const float* proj_b = (const float*)d_in[2];
    const float* ln_g   = (const float*)d_in[3];
    const float* ln_b   = (const float*)d_in[4];
    const float* Wih_f  = (const float*)d_in[5];
    const float* Whh_f  = (const float*)d_in[6];
    const float* bih_f  = (const float*)d_in[7];
    const float* bhh_f  = (const float*)d_in[8];
    const float* Wih_b  = (const float*)d_in[9];
    const float* Whh_b  = (const float*)d_in[10];
    const float* bih_b  = (const float*)d_in[11];
    const float* bhh_b  = (const float*)d_in[12];
    const float* Wih_d  = (const float*)d_in[13];
    const float* Whh_d  = (const float*)d_in[14];
    const float* bih_d  = (const float*)d_in[15];
    const float* bhh_d  = (const float*)d_in[16];
    const float* hb_W   = (const float*)d_in[17];
    const float* hb_b   = (const float*)d_in[18];
    const float* cb_W   = (const float*)d_in[19];
    const float* cb_b   = (const float*)d_in[20];
    const float* gW1    = (const float*)d_in[21];
    const float* gW2    = (const float*)d_in[22];
    const float* gv     = (const float*)d_in[23];
    const float* pW1    = (const float*)d_in[24];
    const float* pW2    = (const float*)d_in[25];
    const float* pv     = (const float*)d_in[26];

    float* ws = (float*)d_ws;
    const size_t o_hT    = 0;
    const size_t o_cT    = 65536;
    const size_t o_h0    = 131072;
    const size_t o_c0    = 163840;
    const size_t o_pre0  = 196608;
    const size_t o_emb   = 0;
    const size_t o_xf    = 4194304;
    const size_t o_xb    = o_xf + 16777216;
    const size_t o_enc   = o_xb + 16777216;
    const size_t o_encW  = o_xf;
    const size_t o_gref  = o_xb;
    const size_t o_pref  = o_xb + 4194304;
    const size_t o_encP  = o_xb + 8388608;

    float* emb  = ws + o_emb;
    float* xf   = ws + o_xf;
    float* xb   = ws + o_xb;
    float* enc  = ws + o_enc;
    float* hT   = ws + o_hT;
    float* cT   = ws + o_cT;
    float* h0b  = ws + o_h0;
    float* c0b  = ws + o_c0;
    float* pre0 = ws + o_pre0;
    float* encW = ws + o_encW;
    float* gref = ws + o_gref;
    float* pref = ws + o_pref;
    float* encP = ws + o_encP;

    float* out_logits = (float*)d_out;
    float* out_ptrs   = out_logits + (size_t)BB * SS * SS;

    // 1. emb
    k_proj_ln<<<BB * SS, 256, 0, stream>>>(x, proj_W, proj_b, ln_g, ln_b, emb);
    // 2-3. xf / xb  (bias = bih + bhh)
    {
        dim3 g(128, 8);
        k_gemm_nt<<<g, 256, 0, stream>>>(emb, 256, Wih_f, xf, 16384, 1024, 256, bih_f, bhh_f, 0);
        k_gemm_nt<<<g, 256, 0, stream>>>(emb, 256, Wih_b, xb, 16384, 1024, 256, bih_b, bhh_b, 0);
    }
    // 4. LSTM both directions: 256 WGs x 512 threads (R12 proven)
    k_lstm<<<256, 512, 0, stream>>>(Whh_f, Whh_b, xf, xb, enc, hT, cT);
    // 5-6. h0 / c0
    {
        dim3 g(1, 2);
        k_gemm_nt<<<g, 256, 0, stream>>>(hT, 512, hb_W, h0b, 128, 256, 512, hb_b, nullptr, 1);
        k_gemm_nt<<<g, 256, 0, stream>>>(cT, 512, cb_W, c0b, 128, 256, 512, cb_b, nullptr, 1);
    }
    // 7-10. attention precomputes
    {
        dim3 g2(128, 2);
        k_gemm_nt<<<g2, 256, 0, stream>>>(enc, 512, gW1, gref, 16384, 256, 512, nullptr, nullptr, 0);
        k_gemm_nt<<<g2, 256, 0, stream>>>(enc, 512, pW1, pref, 16384, 256, 512, nullptr, nullptr, 0);
        dim3 g1(128, 8);
        k_gemm_nt<<<g1, 256, 0, stream>>>(enc, 512, Wih_d, encW, 16384, 1024, 512, bih_d, bhh_d, 0);
        k_gemm_nt<<<g2, 256, 0, stream>>>(enc, 512, pW2, encP, 16384, 256, 256, nullptr, nullptr, 0);
    }
    // 11. pre0 = mean_s encW
    k_meanw<<<BB, 256, 0, stream>>>(encW, pre0);
    // 12. decoder: 128 WGs x 1024 threads, wave-specialized, 7 barriers/step
    k_decoder<<<128, 1024, 0, stream>>>(Whh_d, gW2, pW2, gv, pv, gref, pref, encP, encW,
                                        pre0, h0b, c0b, out_logits, out_ptrs);
}